// Round 19
// baseline (714.338 us; speedup 1.0000x reference)
//
#include <hip/hip_runtime.h>
#include <hip/hip_bf16.h>
#include <math.h>

#define Bb 1024
#define Ll 30
#define Dd 300
#define Hh 20
#define HDd 20

typedef __attribute__((ext_vector_type(8))) short short8;
typedef __attribute__((ext_vector_type(4))) float f32x4;
typedef __attribute__((ext_vector_type(4))) unsigned short u16x4;

// swizzled LDS index: [32 rows][320 u16], 8-u16 chunk XOR (verified: ~6.6e5 conflicts)
#define SW(row, col) ((row)*320 + ((((col) >> 3) ^ ((row) & 7)) << 3) + ((col) & 7))

// ws packing: Q frags [h][nt=19][ks=10][lane=64][8] hi,lo; V [h][nt=2][ks=10][64][8]
#define QELEMS (Hh*19*10*64*8)
#define VELEMS (Hh*2*10*64*8)
#define WS_NEEDED ((size_t)(2*QELEMS + 2*VELEMS) * 2)

__device__ __forceinline__ unsigned short cvt_hi(float x) {
    return __builtin_bit_cast(unsigned short, __float2bfloat16(x));
}
__device__ __forceinline__ void splitc(float x, unsigned short& h, unsigned short& l) {
    h = cvt_hi(x);
    float hf = __uint_as_float((unsigned)h << 16);
    l = cvt_hi(x - hf);
}
// manual RNE split (prep kernels keep the verified path)
__device__ __forceinline__ void bf16split(float x, unsigned short& h, unsigned short& l) {
    unsigned u = __float_as_uint(x);
    unsigned hr = (u + 0x7FFFu + ((u >> 16) & 1u)) >> 16;
    float hf = __uint_as_float(hr << 16);
    float r = x - hf;
    unsigned v = __float_as_uint(r);
    unsigned lr = (v + 0x7FFFu + ((v >> 16) & 1u)) >> 16;
    h = (unsigned short)hr; l = (unsigned short)lr;
}

__global__ void pack_q(const float* __restrict__ Q,
                       unsigned short* __restrict__ qh, unsigned short* __restrict__ ql) {
    int g = blockIdx.x * blockDim.x + threadIdx.x;
    if (g >= Hh*19*10*64) return;
    int l = g & 63;
    int t = g >> 6;
    int ks = t % 10; t /= 10;
    int nt = t % 19; int h = t / 19;
    int e = 16*nt + (l & 15);
    int kbase = 32*ks + 8*(l >> 4);
    unsigned hp[4], lp[4];
    #pragma unroll
    for (int p = 0; p < 4; ++p) {
        int k0 = kbase + 2*p, k1 = k0 + 1;
        float x0 = (k0 < Dd && e < Dd) ? Q[h*Dd*Dd + k0*Dd + e] : 0.f;
        float x1 = (k1 < Dd && e < Dd) ? Q[h*Dd*Dd + k1*Dd + e] : 0.f;
        unsigned short h0,l0,h1,l1;
        bf16split(x0,h0,l0); bf16split(x1,h1,l1);
        hp[p] = (unsigned)h0 | ((unsigned)h1 << 16);
        lp[p] = (unsigned)l0 | ((unsigned)l1 << 16);
    }
    ((uint4*)qh)[g] = make_uint4(hp[0],hp[1],hp[2],hp[3]);
    ((uint4*)ql)[g] = make_uint4(lp[0],lp[1],lp[2],lp[3]);
}

__global__ void pack_v(const float* __restrict__ V,
                       unsigned short* __restrict__ vh, unsigned short* __restrict__ vl) {
    int g = blockIdx.x * blockDim.x + threadIdx.x;
    if (g >= Hh*2*10*64) return;
    int l = g & 63;
    int t = g >> 6;
    int ks = t % 10; t /= 10;
    int nt = t % 2; int h = t / 2;
    int f = 16*nt + (l & 15);
    int kbase = 32*ks + 8*(l >> 4);
    unsigned hp[4], lp[4];
    #pragma unroll
    for (int p = 0; p < 4; ++p) {
        int k0 = kbase + 2*p, k1 = k0 + 1;
        float x0 = (k0 < Dd && f < HDd) ? V[h*Dd*HDd + k0*HDd + f] : 0.f;
        float x1 = (k1 < Dd && f < HDd) ? V[h*Dd*HDd + k1*HDd + f] : 0.f;
        unsigned short h0,l0,h1,l1;
        bf16split(x0,h0,l0); bf16split(x1,h1,l1);
        hp[p] = (unsigned)h0 | ((unsigned)h1 << 16);
        lp[p] = (unsigned)l0 | ((unsigned)l1 << 16);
    }
    ((uint4*)vh)[g] = make_uint4(hp[0],hp[1],hp[2],hp[3]);
    ((uint4*)vl)[g] = make_uint4(lp[0],lp[1],lp[2],lp[3]);
}

// ---- main: one block per (b,h), 512 thr = 8 waves, LDS 81,920 B -> 2 blocks/CU ----
// Round-12 verified structure (708us) + T5 s_setprio(1) around MFMA clusters.
// VGPR must stay <= 64 (measured occupancy cliff at >64: 44% -> 24%).
__global__ __launch_bounds__(512, 2)
void mha_v9(const float* __restrict__ y, const int* __restrict__ seq,
            const unsigned short* __restrict__ qh, const unsigned short* __restrict__ ql,
            const unsigned short* __restrict__ vh, const unsigned short* __restrict__ vl,
            float* __restrict__ out)
{
    __shared__ __align__(16) unsigned short y_h[32*320], y_l[32*320];  // y bf16 hi/lo, swizzled
    __shared__ __align__(16) unsigned short a1h[32*320], a1l[32*320];  // a1 hi/lo; later P^T / alpha

    const int bid = blockIdx.x;
    const int h = bid >> 10, b = bid & 1023;   // b fastest -> consecutive blocks share Q[h] in L2
    const int tid = threadIdx.x;
    const int lane = tid & 63, wid = tid >> 6;
    const int lrow = lane & 15, lk = lane >> 4;
    const int l7 = lrow & 7;

    // ---- phase 1: y -> swizzled bf16 hi/lo LDS, float4-vectorized ----
    const float* yb = y + (size_t)b * (Ll * Dd);
    const float4 z4 = make_float4(0.f, 0.f, 0.f, 0.f);
    for (int idx4 = tid; idx4 < 32*80; idx4 += 512) {
        int row = idx4 / 80;
        int c4  = (idx4 - row*80) << 2;                 // chunks all-valid (<300) or all-pad
        float4 v = (row < Ll && c4 < Dd) ? *reinterpret_cast<const float4*>(yb + row*Dd + c4) : z4;
        unsigned short h0, l0, h1, l1, h2, l2, h3, l3;
        splitc(v.x, h0, l0);
        splitc(v.y, h1, l1);
        splitc(v.z, h2, l2);
        splitc(v.w, h3, l3);
        u16x4 hv, lv;
        hv[0] = h0; hv[1] = h1; hv[2] = h2; hv[3] = h3;
        lv[0] = l0; lv[1] = l1; lv[2] = l2; lv[3] = l3;
        int sidx = SW(row, c4);                         // 4 cols share one 8-chunk; 8B aligned
        *reinterpret_cast<u16x4*>(&y_h[sidx]) = hv;
        *reinterpret_cast<u16x4*>(&y_l[sidx]) = lv;
    }
    if (tid < 128) {   // zero a1 pad chunks 38,39 (cols 304..319) for phase-3 K-tail
        int r = tid & 31, c = 38 + ((tid >> 5) & 1);
        unsigned short* p = (tid >> 6) ? a1l : a1h;
        int sc = c ^ (r & 7);
        *((uint4*)&p[r*320 + sc*8]) = make_uint4(0,0,0,0);
    }
    __syncthreads();

    // ---- phase 2: a1 = y.Q (3-split MFMA); 38 half-tiles (nt, Mt), stride-8 over 8 waves ----
    for (int ht = wid; ht < 38; ht += 8) {
        const int nt = ht >> 1, Mt = ht & 1;
        f32x4 acc0 = (f32x4){0,0,0,0}, acc1 = (f32x4){0,0,0,0};
        const unsigned short* qhp = qh + (size_t)((h*19 + nt)*10)*512 + lane*8;
        const unsigned short* qlp = ql + (size_t)((h*19 + nt)*10)*512 + lane*8;
        const int arow = (16*Mt + lrow)*320;
        __builtin_amdgcn_s_setprio(1);
        #pragma unroll
        for (int ks = 0; ks < 10; ++ks) {
            short8 bh = *(const short8*)(qhp + ks*512);
            short8 bl = *(const short8*)(qlp + ks*512);
            const int ia = arow + (((4*ks + lk) ^ l7) << 3);
            short8 ah = *(const short8*)&y_h[ia];
            short8 al = *(const short8*)&y_l[ia];
            if (ks & 1) {
                acc1 = __builtin_amdgcn_mfma_f32_16x16x32_bf16(ah, bh, acc1, 0,0,0);
                acc1 = __builtin_amdgcn_mfma_f32_16x16x32_bf16(al, bh, acc1, 0,0,0);
                acc1 = __builtin_amdgcn_mfma_f32_16x16x32_bf16(ah, bl, acc1, 0,0,0);
            } else {
                acc0 = __builtin_amdgcn_mfma_f32_16x16x32_bf16(ah, bh, acc0, 0,0,0);
                acc0 = __builtin_amdgcn_mfma_f32_16x16x32_bf16(al, bh, acc0, 0,0,0);
                acc0 = __builtin_amdgcn_mfma_f32_16x16x32_bf16(ah, bl, acc0, 0,0,0);
            }
        }
        __builtin_amdgcn_s_setprio(0);
        f32x4 a = acc0 + acc1;
        const int col = 16*nt + lrow;                   // <= 303 always
        #pragma unroll
        for (int r = 0; r < 4; ++r) {
            int row = 16*Mt + 4*lk + r;
            unsigned short hv, lv; splitc(a[r], hv, lv);
            int sidx = SW(row, col);
            a1h[sidx] = hv;
            a1l[sidx] = lv;
        }
    }
    __syncthreads();

    // ---- phase 3: waves 0-1: S = a1.y^T + in-register softmax; waves 2-5: P = y.V ----
    f32x4 Pacc = (f32x4){0,0,0,0};
    float alf[2][4];

    if (wid < 2) {
        const int Mt = wid;
        f32x4 acc[2][2];  // [Nt][parity]
        #pragma unroll
        for (int i = 0; i < 2; ++i) { acc[i][0] = (f32x4){0,0,0,0}; acc[i][1] = (f32x4){0,0,0,0}; }
        const int arow = (16*Mt + lrow)*320;
        __builtin_amdgcn_s_setprio(1);
        #pragma unroll
        for (int ntp = 0; ntp < 10; ++ntp) {
            const int ch = ((4*ntp + lk) ^ l7) << 3;
            short8 ah = *(const short8*)&a1h[arow + ch];
            short8 al = *(const short8*)&a1l[arow + ch];
            #pragma unroll
            for (int Nt = 0; Nt < 2; ++Nt) {
                int ib = (16*Nt + lrow)*320 + ch;
                short8 bh = *(const short8*)&y_h[ib];
                short8 bl = *(const short8*)&y_l[ib];
                acc[Nt][ntp&1] = __builtin_amdgcn_mfma_f32_16x16x32_bf16(ah, bh, acc[Nt][ntp&1], 0,0,0);
                acc[Nt][ntp&1] = __builtin_amdgcn_mfma_f32_16x16x32_bf16(al, bh, acc[Nt][ntp&1], 0,0,0);
                acc[Nt][ntp&1] = __builtin_amdgcn_mfma_f32_16x16x32_bf16(ah, bl, acc[Nt][ntp&1], 0,0,0);
            }
        }
        __builtin_amdgcn_s_setprio(0);
        f32x4 S0 = acc[0][0] + acc[0][1];
        f32x4 S1 = acc[1][0] + acc[1][1];
        // softmax-ratio (max-shifted; exact algebra vs reference). row q = 16Mt+4lk+r, col m = 16Nt+lrow.
        const float mk0 = (seq[b*Ll + lrow] > 0) ? 1.f : 0.f;
        const float mk1 = (lrow < 14) ? ((seq[b*Ll + 16 + lrow] > 0) ? 1.f : 0.f) : 0.f;
        #pragma unroll
        for (int r = 0; r < 4; ++r) {
            float s0 = S0[r], s1 = S1[r];
            float v = fmaxf(s0, (lrow < 14) ? s1 : -3.4e38f);
            #pragma unroll
            for (int off = 8; off >= 1; off >>= 1)
                v = fmaxf(v, __shfl_xor(v, off, 64));
            float e0 = __expf(s0 - v);
            float e1 = __expf(s1 - v);
            float sum = e0 * mk0 + e1 * mk1;
            #pragma unroll
            for (int off = 8; off >= 1; off >>= 1)
                sum += __shfl_xor(sum, off, 64);
            float denom = sum + 1e-6f * __expf(-v);
            alf[0][r] = e0 / denom;
            alf[1][r] = (lrow < 14) ? e1 / denom : 0.f;   // zero artifact cols m=30,31
        }
    } else if (wid < 6) {
        const int w = wid - 2, Mtp = w >> 1, Ntp = w & 1;
        f32x4 acc0 = (f32x4){0,0,0,0}, acc1 = (f32x4){0,0,0,0};
        const unsigned short* vhp = vh + (size_t)((h*2 + Ntp)*10)*512 + lane*8;
        const unsigned short* vlp = vl + (size_t)((h*2 + Ntp)*10)*512 + lane*8;
        const int arow = (16*Mtp + lrow)*320;
        __builtin_amdgcn_s_setprio(1);
        #pragma unroll
        for (int ks = 0; ks < 10; ++ks) {
            short8 bh = *(const short8*)(vhp + ks*512);
            short8 bl = *(const short8*)(vlp + ks*512);
            int ia = arow + (((4*ks + lk) ^ l7) << 3);
            short8 ah = *(const short8*)&y_h[ia];
            short8 al = *(const short8*)&y_l[ia];
            if (ks & 1) {
                acc1 = __builtin_amdgcn_mfma_f32_16x16x32_bf16(ah, bh, acc1, 0,0,0);
                acc1 = __builtin_amdgcn_mfma_f32_16x16x32_bf16(al, bh, acc1, 0,0,0);
                acc1 = __builtin_amdgcn_mfma_f32_16x16x32_bf16(ah, bl, acc1, 0,0,0);
            } else {
                acc0 = __builtin_amdgcn_mfma_f32_16x16x32_bf16(ah, bh, acc0, 0,0,0);
                acc0 = __builtin_amdgcn_mfma_f32_16x16x32_bf16(al, bh, acc0, 0,0,0);
                acc0 = __builtin_amdgcn_mfma_f32_16x16x32_bf16(ah, bl, acc0, 0,0,0);
            }
        }
        __builtin_amdgcn_s_setprio(0);
        Pacc = acc0 + acc1;
    }
    __syncthreads();   // S-waves done reading a1 -> a1h/a1l reusable

    // ---- phase 4: alpha -> a1l [q][m] bf16 (waves 0-1); P^T -> a1h [f][m] bf16 (waves 2-5) ----
    if (wid < 2) {
        const int Mt = wid;
        #pragma unroll
        for (int Nt = 0; Nt < 2; ++Nt)
            #pragma unroll
            for (int r = 0; r < 4; ++r)
                a1l[SW(16*Mt + 4*lk + r, 16*Nt + lrow)] = cvt_hi(alf[Nt][r]);
    } else if (wid < 6) {
        const int w = wid - 2, Mtp = w >> 1, Ntp = w & 1;
        #pragma unroll
        for (int r = 0; r < 4; ++r)
            a1h[SW(16*Ntp + lrow, 16*Mtp + 4*lk + r)] = cvt_hi(Pacc[r]);
        // P^T rows m=30,31 never written, but alpha cols 30,31 are zero -> unused
    }
    __syncthreads();

    // ---- phase 5: out = alpha . P ; waves 0-3 = quadrants ----
    if (wid < 4) {
        const int Mt = wid >> 1, Nt = wid & 1;
        short8 af = *(const short8*)&a1l[(16*Mt + lrow)*320 + ((lk ^ l7) << 3)];
        short8 pf = *(const short8*)&a1h[(16*Nt + lrow)*320 + ((lk ^ l7) << 3)];
        f32x4 O = __builtin_amdgcn_mfma_f32_16x16x32_bf16(af, pf, (f32x4){0,0,0,0}, 0,0,0);
        #pragma unroll
        for (int r = 0; r < 4; ++r) {
            int q = 16*Mt + 4*lk + r;
            int f = 16*Nt + lrow;
            if (q < Ll && f < HDd)
                out[(size_t)b*(Ll*Hh*HDd) + q*(Hh*HDd) + h*HDd + f] = O[r];
        }
    }
}

// ---- fallback (round-5 verified fp32 kernel), used if ws too small ----
__global__ __launch_bounds__(256, 3)
void mha_fused_fp32(const float* __restrict__ y,
                    const int* __restrict__ seq,
                    const float* __restrict__ Q,
                    const float* __restrict__ V,
                    float* __restrict__ out)
{
    __shared__ float ys[32][320];
    __shared__ float alphaS[32][33];
    __shared__ float Plds[32][20];
    __shared__ float maskSf[32];

    const int bid = blockIdx.x;
    const int h = bid >> 10;
    const int b = bid & 1023;
    const int tid = threadIdx.x;
    const int tj = tid & 31;
    const int ti = tid >> 5;
    const int r0 = ti * 4;

    const float* yb = y + b * (Ll * Dd);
    for (int i = tid; i < 32 * 320; i += 256) {
        int row = i / 320;
        int col = i - row * 320;
        float v = 0.f;
        if (row < Ll && col < Dd) v = yb[row * Dd + col];
        ys[row][col] = v;
    }
    if (tid < 32) {
        float m = 0.f;
        if (tid < Ll) m = (seq[b * Ll + tid] > 0) ? 1.f : 0.f;
        maskSf[tid] = m;
    }
    __syncthreads();

    float a1reg[4][10];
    #pragma unroll
    for (int r = 0; r < 4; ++r)
        #pragma unroll
        for (int k = 0; k < 10; ++k) a1reg[r][k] = 0.f;

    const float* Qh = Q + h * (Dd * Dd) + tj;
    for (int d0 = 0; d0 < Dd; d0 += 4) {
        float ysv[4][4];
        #pragma unroll
        for (int r = 0; r < 4; ++r) {
            float4 t = *reinterpret_cast<const float4*>(&ys[r0 + r][d0]);
            ysv[r][0] = t.x; ysv[r][1] = t.y; ysv[r][2] = t.z; ysv[r][3] = t.w;
        }
        #pragma unroll
        for (int dd = 0; dd < 4; ++dd) {
            const float* qp = Qh + (d0 + dd) * Dd;
            float qv[10];
            #pragma unroll
            for (int k = 0; k < 9; ++k) qv[k] = qp[32 * k];
            qv[9] = (tj < 12) ? qp[288] : 0.f;
            #pragma unroll
            for (int r = 0; r < 4; ++r) {
                float yd = ysv[r][dd];
                #pragma unroll
                for (int k = 0; k < 10; ++k)
                    a1reg[r][k] = fmaf(yd, qv[k], a1reg[r][k]);
            }
        }
    }

    float Sreg[4] = {0.f, 0.f, 0.f, 0.f};
    for (int m = 0; m < Ll; ++m) {
        float yv[10];
        #pragma unroll
        for (int k = 0; k < 10; ++k) yv[k] = ys[m][tj + 32 * k];
        float part[4];
        #pragma unroll
        for (int r = 0; r < 4; ++r) {
            float s = 0.f;
            #pragma unroll
            for (int k = 0; k < 10; ++k) s = fmaf(a1reg[r][k], yv[k], s);
            part[r] = s;
        }
        #pragma unroll
        for (int off = 16; off >= 1; off >>= 1)
            #pragma unroll
            for (int r = 0; r < 4; ++r)
                part[r] += __shfl_xor(part[r], off, 64);
        #pragma unroll
        for (int r = 0; r < 4; ++r)
            if (tj == m) Sreg[r] = part[r];
    }

    const float maskv = maskSf[tj];
    float Areg[4];
    #pragma unroll
    for (int r = 0; r < 4; ++r) {
        float v = (tj < Ll) ? Sreg[r] : -3.4e38f;
        #pragma unroll
        for (int off = 16; off >= 1; off >>= 1)
            v = fmaxf(v, __shfl_xor(v, off, 64));
        float e = __expf(Sreg[r] - v);
        float s = (tj < Ll) ? e * maskv : 0.f;
        #pragma unroll
        for (int off = 16; off >= 1; off >>= 1)
            s += __shfl_xor(s, off, 64);
        float denom = s + 1e-6f * __expf(-v);
        Areg[r] = e / denom;
    }
    #pragma unroll
    for (int r = 0; r < 4; ++r)
        if (r0 + r < Ll && tj < Ll) alphaS[r0 + r][tj] = Areg[r];

    float Pacc[4] = {0.f, 0.f, 0.f, 0.f};
    if (tj < HDd) {
        const float* Vh = V + h * (Dd * HDd) + tj;
        for (int d0 = 0; d0 < Dd; d0 += 4) {
            float ysv[4][4];
            #pragma unroll
            for (int r = 0; r < 4; ++r) {
                float4 t = *reinterpret_cast<const float4*>(&ys[r0 + r][d0]);
                ysv[r][0] = t.x; ysv[r][1] = t.y; ysv[r][2] = t.z; ysv[r][3] = t.w;
            }
            float vv[4];
            #pragma unroll
            for (int dd = 0; dd < 4; ++dd) vv[dd] = Vh[(d0 + dd) * HDd];
            #pragma unroll
            for (int r = 0; r < 4; ++r)
                #pragma unroll
                for (int dd = 0; dd < 4; ++dd)
                    Pacc[r] = fmaf(ysv[r][dd], vv[dd], Pacc[r]);
        }
    }
    #pragma unroll
    for (int r = 0; r < 4; ++r)
        if (tj < HDd && r0 + r < Ll) Plds[r0 + r][tj] = Pacc[r];
    __syncthreads();

    float* outb = out + b * (Ll * Hh * HDd) + h * HDd;
    for (int t = tid; t < Ll * HDd; t += 256) {
        int l = t / HDd;
        int f = t - l * HDd;
        float acc = 0.f;
        #pragma unroll
        for (int m = 0; m < Ll; ++m)
            acc = fmaf(alphaS[l][m], Plds[m][f], acc);
        outb[l * (Hh * HDd) + f] = acc;
    }
}

extern "C" void kernel_launch(void* const* d_in, const int* in_sizes, int n_in,
                              void* d_out, int out_size, void* d_ws, size_t ws_size,
                              hipStream_t stream) {
    (void)in_sizes; (void)n_in; (void)out_size;
    const float* y   = (const float*)d_in[0];
    const int*   seq = (const int*)d_in[1];
    const float* Q   = (const float*)d_in[2];
    const float* V   = (const float*)d_in[3];
    float* out = (float*)d_out;

    if (ws_size < WS_NEEDED) {
        hipLaunchKernelGGL(mha_fused_fp32, dim3(Bb * Hh), dim3(256), 0, stream, y, seq, Q, V, out);
        return;
    }

    unsigned short* qh = (unsigned short*)d_ws;
    unsigned short* ql = qh + QELEMS;
    unsigned short* vh = ql + QELEMS;
    unsigned short* vl = vh + VELEMS;

    pack_q<<<dim3((Hh*19*10*64 + 255)/256), dim3(256), 0, stream>>>(Q, qh, ql);
    pack_v<<<dim3((Hh*2*10*64 + 255)/256), dim3(256), 0, stream>>>(V, vh, vl);
    mha_v9<<<dim3(Bb * Hh), dim3(512), 0, stream>>>(y, seq, qh, ql, vh, vl, out);
}

// Round 20
// 708.337 us; speedup vs baseline: 1.0085x; 1.0085x over previous
//
#include <hip/hip_runtime.h>
#include <hip/hip_bf16.h>
#include <math.h>

#define Bb 1024
#define Ll 30
#define Dd 300
#define Hh 20
#define HDd 20

typedef __attribute__((ext_vector_type(8))) short short8;
typedef __attribute__((ext_vector_type(4))) float f32x4;
typedef __attribute__((ext_vector_type(4))) unsigned short u16x4;

// swizzled LDS index: [32 rows][320 u16], 8-u16 chunk XOR (verified: ~6.6e5 conflicts)
#define SW(row, col) ((row)*320 + ((((col) >> 3) ^ ((row) & 7)) << 3) + ((col) & 7))

// ws packing: Q frags [h][nt=19][ks=10][lane=64][8] hi,lo; V [h][nt=2][ks=10][64][8]
#define QELEMS (Hh*19*10*64*8)
#define VELEMS (Hh*2*10*64*8)
#define WS_NEEDED ((size_t)(2*QELEMS + 2*VELEMS) * 2)

__device__ __forceinline__ unsigned short cvt_hi(float x) {
    return __builtin_bit_cast(unsigned short, __float2bfloat16(x));
}
__device__ __forceinline__ void splitc(float x, unsigned short& h, unsigned short& l) {
    h = cvt_hi(x);
    float hf = __uint_as_float((unsigned)h << 16);
    l = cvt_hi(x - hf);
}
// manual RNE split (prep kernels keep the verified path)
__device__ __forceinline__ void bf16split(float x, unsigned short& h, unsigned short& l) {
    unsigned u = __float_as_uint(x);
    unsigned hr = (u + 0x7FFFu + ((u >> 16) & 1u)) >> 16;
    float hf = __uint_as_float(hr << 16);
    float r = x - hf;
    unsigned v = __float_as_uint(r);
    unsigned lr = (v + 0x7FFFu + ((v >> 16) & 1u)) >> 16;
    h = (unsigned short)hr; l = (unsigned short)lr;
}

__global__ void pack_q(const float* __restrict__ Q,
                       unsigned short* __restrict__ qh, unsigned short* __restrict__ ql) {
    int g = blockIdx.x * blockDim.x + threadIdx.x;
    if (g >= Hh*19*10*64) return;
    int l = g & 63;
    int t = g >> 6;
    int ks = t % 10; t /= 10;
    int nt = t % 19; int h = t / 19;
    int e = 16*nt + (l & 15);
    int kbase = 32*ks + 8*(l >> 4);
    unsigned hp[4], lp[4];
    #pragma unroll
    for (int p = 0; p < 4; ++p) {
        int k0 = kbase + 2*p, k1 = k0 + 1;
        float x0 = (k0 < Dd && e < Dd) ? Q[h*Dd*Dd + k0*Dd + e] : 0.f;
        float x1 = (k1 < Dd && e < Dd) ? Q[h*Dd*Dd + k1*Dd + e] : 0.f;
        unsigned short h0,l0,h1,l1;
        bf16split(x0,h0,l0); bf16split(x1,h1,l1);
        hp[p] = (unsigned)h0 | ((unsigned)h1 << 16);
        lp[p] = (unsigned)l0 | ((unsigned)l1 << 16);
    }
    ((uint4*)qh)[g] = make_uint4(hp[0],hp[1],hp[2],hp[3]);
    ((uint4*)ql)[g] = make_uint4(lp[0],lp[1],lp[2],lp[3]);
}

__global__ void pack_v(const float* __restrict__ V,
                       unsigned short* __restrict__ vh, unsigned short* __restrict__ vl) {
    int g = blockIdx.x * blockDim.x + threadIdx.x;
    if (g >= Hh*2*10*64) return;
    int l = g & 63;
    int t = g >> 6;
    int ks = t % 10; t /= 10;
    int nt = t % 2; int h = t / 2;
    int f = 16*nt + (l & 15);
    int kbase = 32*ks + 8*(l >> 4);
    unsigned hp[4], lp[4];
    #pragma unroll
    for (int p = 0; p < 4; ++p) {
        int k0 = kbase + 2*p, k1 = k0 + 1;
        float x0 = (k0 < Dd && f < HDd) ? V[h*Dd*HDd + k0*HDd + f] : 0.f;
        float x1 = (k1 < Dd && f < HDd) ? V[h*Dd*HDd + k1*HDd + f] : 0.f;
        unsigned short h0,l0,h1,l1;
        bf16split(x0,h0,l0); bf16split(x1,h1,l1);
        hp[p] = (unsigned)h0 | ((unsigned)h1 << 16);
        lp[p] = (unsigned)l0 | ((unsigned)l1 << 16);
    }
    ((uint4*)vh)[g] = make_uint4(hp[0],hp[1],hp[2],hp[3]);
    ((uint4*)vl)[g] = make_uint4(lp[0],lp[1],lp[2],lp[3]);
}

// ---- main: one block per (b,h), 512 thr = 8 waves, LDS 81,920 B -> 2 blocks/CU ----
// FINAL VERIFIED BEST (round 12/18: 708-712 us, VGPR 56, occ 44%).
// Measured constraints documented this session:
//  - VGPR <= 64 required: occupancy cliff at >64 (44% -> 24%; rounds 13/17).
//  - Phase-max arithmetic: barriers separate phases, so per-phase MAXIMA add;
//    cross-phase rebalance is a no-op (round 16).
//  - Head-pairing/reg-prefetch push VGPR past the cliff (rounds 13/17).
//  - s_setprio: null on this barrier-locked structure (round 19).
__global__ __launch_bounds__(512, 2)
void mha_v5(const float* __restrict__ y, const int* __restrict__ seq,
            const unsigned short* __restrict__ qh, const unsigned short* __restrict__ ql,
            const unsigned short* __restrict__ vh, const unsigned short* __restrict__ vl,
            float* __restrict__ out)
{
    __shared__ __align__(16) unsigned short y_h[32*320], y_l[32*320];  // y bf16 hi/lo, swizzled
    __shared__ __align__(16) unsigned short a1h[32*320], a1l[32*320];  // a1 hi/lo; later P^T / alpha

    const int bid = blockIdx.x;
    const int h = bid >> 10, b = bid & 1023;   // b fastest -> consecutive blocks share Q[h] in L2
    const int tid = threadIdx.x;
    const int lane = tid & 63, wid = tid >> 6;
    const int lrow = lane & 15, lk = lane >> 4;
    const int l7 = lrow & 7;

    // ---- phase 1: y -> swizzled bf16 hi/lo LDS, float4-vectorized ----
    const float* yb = y + (size_t)b * (Ll * Dd);
    const float4 z4 = make_float4(0.f, 0.f, 0.f, 0.f);
    for (int idx4 = tid; idx4 < 32*80; idx4 += 512) {
        int row = idx4 / 80;
        int c4  = (idx4 - row*80) << 2;                 // chunks all-valid (<300) or all-pad
        float4 v = (row < Ll && c4 < Dd) ? *reinterpret_cast<const float4*>(yb + row*Dd + c4) : z4;
        unsigned short h0, l0, h1, l1, h2, l2, h3, l3;
        splitc(v.x, h0, l0);
        splitc(v.y, h1, l1);
        splitc(v.z, h2, l2);
        splitc(v.w, h3, l3);
        u16x4 hv, lv;
        hv[0] = h0; hv[1] = h1; hv[2] = h2; hv[3] = h3;
        lv[0] = l0; lv[1] = l1; lv[2] = l2; lv[3] = l3;
        int sidx = SW(row, c4);                         // 4 cols share one 8-chunk; 8B aligned
        *reinterpret_cast<u16x4*>(&y_h[sidx]) = hv;
        *reinterpret_cast<u16x4*>(&y_l[sidx]) = lv;
    }
    if (tid < 128) {   // zero a1 pad chunks 38,39 (cols 304..319) for phase-3 K-tail
        int r = tid & 31, c = 38 + ((tid >> 5) & 1);
        unsigned short* p = (tid >> 6) ? a1l : a1h;
        int sc = c ^ (r & 7);
        *((uint4*)&p[r*320 + sc*8]) = make_uint4(0,0,0,0);
    }
    __syncthreads();

    // ---- phase 2: a1 = y.Q (3-split MFMA); 38 half-tiles (nt, Mt), stride-8 over 8 waves ----
    for (int ht = wid; ht < 38; ht += 8) {
        const int nt = ht >> 1, Mt = ht & 1;
        f32x4 acc0 = (f32x4){0,0,0,0}, acc1 = (f32x4){0,0,0,0};
        const unsigned short* qhp = qh + (size_t)((h*19 + nt)*10)*512 + lane*8;
        const unsigned short* qlp = ql + (size_t)((h*19 + nt)*10)*512 + lane*8;
        const int arow = (16*Mt + lrow)*320;
        #pragma unroll
        for (int ks = 0; ks < 10; ++ks) {
            short8 bh = *(const short8*)(qhp + ks*512);
            short8 bl = *(const short8*)(qlp + ks*512);
            const int ia = arow + (((4*ks + lk) ^ l7) << 3);
            short8 ah = *(const short8*)&y_h[ia];
            short8 al = *(const short8*)&y_l[ia];
            if (ks & 1) {
                acc1 = __builtin_amdgcn_mfma_f32_16x16x32_bf16(ah, bh, acc1, 0,0,0);
                acc1 = __builtin_amdgcn_mfma_f32_16x16x32_bf16(al, bh, acc1, 0,0,0);
                acc1 = __builtin_amdgcn_mfma_f32_16x16x32_bf16(ah, bl, acc1, 0,0,0);
            } else {
                acc0 = __builtin_amdgcn_mfma_f32_16x16x32_bf16(ah, bh, acc0, 0,0,0);
                acc0 = __builtin_amdgcn_mfma_f32_16x16x32_bf16(al, bh, acc0, 0,0,0);
                acc0 = __builtin_amdgcn_mfma_f32_16x16x32_bf16(ah, bl, acc0, 0,0,0);
            }
        }
        f32x4 a = acc0 + acc1;
        const int col = 16*nt + lrow;                   // <= 303 always
        #pragma unroll
        for (int r = 0; r < 4; ++r) {
            int row = 16*Mt + 4*lk + r;
            unsigned short hv, lv; splitc(a[r], hv, lv);
            int sidx = SW(row, col);
            a1h[sidx] = hv;
            a1l[sidx] = lv;
        }
    }
    __syncthreads();

    // ---- phase 3: waves 0-1: S = a1.y^T + in-register softmax; waves 2-5: P = y.V ----
    f32x4 Pacc = (f32x4){0,0,0,0};
    float alf[2][4];

    if (wid < 2) {
        const int Mt = wid;
        f32x4 acc[2][2];  // [Nt][parity]
        #pragma unroll
        for (int i = 0; i < 2; ++i) { acc[i][0] = (f32x4){0,0,0,0}; acc[i][1] = (f32x4){0,0,0,0}; }
        const int arow = (16*Mt + lrow)*320;
        #pragma unroll
        for (int ntp = 0; ntp < 10; ++ntp) {
            const int ch = ((4*ntp + lk) ^ l7) << 3;
            short8 ah = *(const short8*)&a1h[arow + ch];
            short8 al = *(const short8*)&a1l[arow + ch];
            #pragma unroll
            for (int Nt = 0; Nt < 2; ++Nt) {
                int ib = (16*Nt + lrow)*320 + ch;
                short8 bh = *(const short8*)&y_h[ib];
                short8 bl = *(const short8*)&y_l[ib];
                acc[Nt][ntp&1] = __builtin_amdgcn_mfma_f32_16x16x32_bf16(ah, bh, acc[Nt][ntp&1], 0,0,0);
                acc[Nt][ntp&1] = __builtin_amdgcn_mfma_f32_16x16x32_bf16(al, bh, acc[Nt][ntp&1], 0,0,0);
                acc[Nt][ntp&1] = __builtin_amdgcn_mfma_f32_16x16x32_bf16(ah, bl, acc[Nt][ntp&1], 0,0,0);
            }
        }
        f32x4 S0 = acc[0][0] + acc[0][1];
        f32x4 S1 = acc[1][0] + acc[1][1];
        // softmax-ratio (max-shifted; exact algebra vs reference). row q = 16Mt+4lk+r, col m = 16Nt+lrow.
        const float mk0 = (seq[b*Ll + lrow] > 0) ? 1.f : 0.f;
        const float mk1 = (lrow < 14) ? ((seq[b*Ll + 16 + lrow] > 0) ? 1.f : 0.f) : 0.f;
        #pragma unroll
        for (int r = 0; r < 4; ++r) {
            float s0 = S0[r], s1 = S1[r];
            float v = fmaxf(s0, (lrow < 14) ? s1 : -3.4e38f);
            #pragma unroll
            for (int off = 8; off >= 1; off >>= 1)
                v = fmaxf(v, __shfl_xor(v, off, 64));
            float e0 = __expf(s0 - v);
            float e1 = __expf(s1 - v);
            float sum = e0 * mk0 + e1 * mk1;
            #pragma unroll
            for (int off = 8; off >= 1; off >>= 1)
                sum += __shfl_xor(sum, off, 64);
            float denom = sum + 1e-6f * __expf(-v);
            alf[0][r] = e0 / denom;
            alf[1][r] = (lrow < 14) ? e1 / denom : 0.f;   // zero artifact cols m=30,31
        }
    } else if (wid < 6) {
        const int w = wid - 2, Mtp = w >> 1, Ntp = w & 1;
        f32x4 acc0 = (f32x4){0,0,0,0}, acc1 = (f32x4){0,0,0,0};
        const unsigned short* vhp = vh + (size_t)((h*2 + Ntp)*10)*512 + lane*8;
        const unsigned short* vlp = vl + (size_t)((h*2 + Ntp)*10)*512 + lane*8;
        const int arow = (16*Mtp + lrow)*320;
        #pragma unroll
        for (int ks = 0; ks < 10; ++ks) {
            short8 bh = *(const short8*)(vhp + ks*512);
            short8 bl = *(const short8*)(vlp + ks*512);
            int ia = arow + (((4*ks + lk) ^ l7) << 3);
            short8 ah = *(const short8*)&y_h[ia];
            short8 al = *(const short8*)&y_l[ia];
            if (ks & 1) {
                acc1 = __builtin_amdgcn_mfma_f32_16x16x32_bf16(ah, bh, acc1, 0,0,0);
                acc1 = __builtin_amdgcn_mfma_f32_16x16x32_bf16(al, bh, acc1, 0,0,0);
                acc1 = __builtin_amdgcn_mfma_f32_16x16x32_bf16(ah, bl, acc1, 0,0,0);
            } else {
                acc0 = __builtin_amdgcn_mfma_f32_16x16x32_bf16(ah, bh, acc0, 0,0,0);
                acc0 = __builtin_amdgcn_mfma_f32_16x16x32_bf16(al, bh, acc0, 0,0,0);
                acc0 = __builtin_amdgcn_mfma_f32_16x16x32_bf16(ah, bl, acc0, 0,0,0);
            }
        }
        Pacc = acc0 + acc1;
    }
    __syncthreads();   // S-waves done reading a1 -> a1h/a1l reusable

    // ---- phase 4: alpha -> a1l [q][m] bf16 (waves 0-1); P^T -> a1h [f][m] bf16 (waves 2-5) ----
    if (wid < 2) {
        const int Mt = wid;
        #pragma unroll
        for (int Nt = 0; Nt < 2; ++Nt)
            #pragma unroll
            for (int r = 0; r < 4; ++r)
                a1l[SW(16*Mt + 4*lk + r, 16*Nt + lrow)] = cvt_hi(alf[Nt][r]);
    } else if (wid < 6) {
        const int w = wid - 2, Mtp = w >> 1, Ntp = w & 1;
        #pragma unroll
        for (int r = 0; r < 4; ++r)
            a1h[SW(16*Ntp + lrow, 16*Mtp + 4*lk + r)] = cvt_hi(Pacc[r]);
        // P^T rows m=30,31 never written, but alpha cols 30,31 are zero -> unused
    }
    __syncthreads();

    // ---- phase 5: out = alpha . P ; waves 0-3 = quadrants ----
    if (wid < 4) {
        const int Mt = wid >> 1, Nt = wid & 1;
        short8 af = *(const short8*)&a1l[(16*Mt + lrow)*320 + ((lk ^ l7) << 3)];
        short8 pf = *(const short8*)&a1h[(16*Nt + lrow)*320 + ((lk ^ l7) << 3)];
        f32x4 O = __builtin_amdgcn_mfma_f32_16x16x32_bf16(af, pf, (f32x4){0,0,0,0}, 0,0,0);
        #pragma unroll
        for (int r = 0; r < 4; ++r) {
            int q = 16*Mt + 4*lk + r;
            int f = 16*Nt + lrow;
            if (q < Ll && f < HDd)
                out[(size_t)b*(Ll*Hh*HDd) + q*(Hh*HDd) + h*HDd + f] = O[r];
        }
    }
}

// ---- fallback (round-5 verified fp32 kernel), used if ws too small ----
__global__ __launch_bounds__(256, 3)
void mha_fused_fp32(const float* __restrict__ y,
                    const int* __restrict__ seq,
                    const float* __restrict__ Q,
                    const float* __restrict__ V,
                    float* __restrict__ out)
{
    __shared__ float ys[32][320];
    __shared__ float alphaS[32][33];
    __shared__ float Plds[32][20];
    __shared__ float maskSf[32];

    const int bid = blockIdx.x;
    const int h = bid >> 10;
    const int b = bid & 1023;
    const int tid = threadIdx.x;
    const int tj = tid & 31;
    const int ti = tid >> 5;
    const int r0 = ti * 4;

    const float* yb = y + b * (Ll * Dd);
    for (int i = tid; i < 32 * 320; i += 256) {
        int row = i / 320;
        int col = i - row * 320;
        float v = 0.f;
        if (row < Ll && col < Dd) v = yb[row * Dd + col];
        ys[row][col] = v;
    }
    if (tid < 32) {
        float m = 0.f;
        if (tid < Ll) m = (seq[b * Ll + tid] > 0) ? 1.f : 0.f;
        maskSf[tid] = m;
    }
    __syncthreads();

    float a1reg[4][10];
    #pragma unroll
    for (int r = 0; r < 4; ++r)
        #pragma unroll
        for (int k = 0; k < 10; ++k) a1reg[r][k] = 0.f;

    const float* Qh = Q + h * (Dd * Dd) + tj;
    for (int d0 = 0; d0 < Dd; d0 += 4) {
        float ysv[4][4];
        #pragma unroll
        for (int r = 0; r < 4; ++r) {
            float4 t = *reinterpret_cast<const float4*>(&ys[r0 + r][d0]);
            ysv[r][0] = t.x; ysv[r][1] = t.y; ysv[r][2] = t.z; ysv[r][3] = t.w;
        }
        #pragma unroll
        for (int dd = 0; dd < 4; ++dd) {
            const float* qp = Qh + (d0 + dd) * Dd;
            float qv[10];
            #pragma unroll
            for (int k = 0; k < 9; ++k) qv[k] = qp[32 * k];
            qv[9] = (tj < 12) ? qp[288] : 0.f;
            #pragma unroll
            for (int r = 0; r < 4; ++r) {
                float yd = ysv[r][dd];
                #pragma unroll
                for (int k = 0; k < 10; ++k)
                    a1reg[r][k] = fmaf(yd, qv[k], a1reg[r][k]);
            }
        }
    }

    float Sreg[4] = {0.f, 0.f, 0.f, 0.f};
    for (int m = 0; m < Ll; ++m) {
        float yv[10];
        #pragma unroll
        for (int k = 0; k < 10; ++k) yv[k] = ys[m][tj + 32 * k];
        float part[4];
        #pragma unroll
        for (int r = 0; r < 4; ++r) {
            float s = 0.f;
            #pragma unroll
            for (int k = 0; k < 10; ++k) s = fmaf(a1reg[r][k], yv[k], s);
            part[r] = s;
        }
        #pragma unroll
        for (int off = 16; off >= 1; off >>= 1)
            #pragma unroll
            for (int r = 0; r < 4; ++r)
                part[r] += __shfl_xor(part[r], off, 64);
        #pragma unroll
        for (int r = 0; r < 4; ++r)
            if (tj == m) Sreg[r] = part[r];
    }

    const float maskv = maskSf[tj];
    float Areg[4];
    #pragma unroll
    for (int r = 0; r < 4; ++r) {
        float v = (tj < Ll) ? Sreg[r] : -3.4e38f;
        #pragma unroll
        for (int off = 16; off >= 1; off >>= 1)
            v = fmaxf(v, __shfl_xor(v, off, 64));
        float e = __expf(Sreg[r] - v);
        float s = (tj < Ll) ? e * maskv : 0.f;
        #pragma unroll
        for (int off = 16; off >= 1; off >>= 1)
            s += __shfl_xor(s, off, 64);
        float denom = s + 1e-6f * __expf(-v);
        Areg[r] = e / denom;
    }
    #pragma unroll
    for (int r = 0; r < 4; ++r)
        if (r0 + r < Ll && tj < Ll) alphaS[r0 + r][tj] = Areg[r];

    float Pacc[4] = {0.f, 0.f, 0.f, 0.f};
    if (tj < HDd) {
        const float* Vh = V + h * (Dd * HDd) + tj;
        for (int d0 = 0; d0 < Dd; d0 += 4) {
            float ysv[4][4];
            #pragma unroll
            for (int r = 0; r < 4; ++r) {
                float4 t = *reinterpret_cast<const float4*>(&ys[r0 + r][d0]);
                ysv[r][0] = t.x; ysv[r][1] = t.y; ysv[r][2] = t.z; ysv[r][3] = t.w;
            }
            float vv[4];
            #pragma unroll
            for (int dd = 0; dd < 4; ++dd) vv[dd] = Vh[(d0 + dd) * HDd];
            #pragma unroll
            for (int r = 0; r < 4; ++r)
                #pragma unroll
                for (int dd = 0; dd < 4; ++dd)
                    Pacc[r] = fmaf(ysv[r][dd], vv[dd], Pacc[r]);
        }
    }
    #pragma unroll
    for (int r = 0; r < 4; ++r)
        if (tj < HDd && r0 + r < Ll) Plds[r0 + r][tj] = Pacc[r];
    __syncthreads();

    float* outb = out + b * (Ll * Hh * HDd) + h * HDd;
    for (int t = tid; t < Ll * HDd; t += 256) {
        int l = t / HDd;
        int f = t - l * HDd;
        float acc = 0.f;
        #pragma unroll
        for (int m = 0; m < Ll; ++m)
            acc = fmaf(alphaS[l][m], Plds[m][f], acc);
        outb[l * (Hh * HDd) + f] = acc;
    }
}

extern "C" void kernel_launch(void* const* d_in, const int* in_sizes, int n_in,
                              void* d_out, int out_size, void* d_ws, size_t ws_size,
                              hipStream_t stream) {
    (void)in_sizes; (void)n_in; (void)out_size;
    const float* y   = (const float*)d_in[0];
    const int*   seq = (const int*)d_in[1];
    const float* Q   = (const float*)d_in[2];
    const float* V   = (const float*)d_in[3];
    float* out = (float*)d_out;

    if (ws_size < WS_NEEDED) {
        hipLaunchKernelGGL(mha_fused_fp32, dim3(Bb * Hh), dim3(256), 0, stream, y, seq, Q, V, out);
        return;
    }

    unsigned short* qh = (unsigned short*)d_ws;
    unsigned short* ql = qh + QELEMS;
    unsigned short* vh = ql + QELEMS;
    unsigned short* vl = vh + VELEMS;

    pack_q<<<dim3((Hh*19*10*64 + 255)/256), dim3(256), 0, stream>>>(Q, qh, ql);
    pack_v<<<dim3((Hh*2*10*64 + 255)/256), dim3(256), 0, stream>>>(V, vh, vl);
    mha_v5<<<dim3(Bb * Hh), dim3(512), 0, stream>>>(y, seq, qh, ql, vh, vl, out);
}

// Round 21
// 706.612 us; speedup vs baseline: 1.0109x; 1.0024x over previous
//
#include <hip/hip_runtime.h>
#include <hip/hip_bf16.h>
#include <math.h>

#define Bb 1024
#define Ll 30
#define Dd 300
#define Hh 20
#define HDd 20

typedef __attribute__((ext_vector_type(8))) short short8;
typedef __attribute__((ext_vector_type(4))) float f32x4;
typedef __attribute__((ext_vector_type(4))) unsigned short u16x4;

// swizzled LDS index: [32 rows][320 u16], 8-u16 chunk XOR (verified: ~6.6e5 conflicts)
#define SW(row, col) ((row)*320 + ((((col) >> 3) ^ ((row) & 7)) << 3) + ((col) & 7))

// ws packing: Q frags [h][nt=19][ks=10][lane=64][8] hi,lo; V [h][nt=2][ks=10][64][8]
#define QELEMS (Hh*19*10*64*8)
#define VELEMS (Hh*2*10*64*8)
#define WS_NEEDED ((size_t)(2*QELEMS + 2*VELEMS) * 2)

__device__ __forceinline__ unsigned short cvt_hi(float x) {
    return __builtin_bit_cast(unsigned short, __float2bfloat16(x));
}
__device__ __forceinline__ void splitc(float x, unsigned short& h, unsigned short& l) {
    h = cvt_hi(x);
    float hf = __uint_as_float((unsigned)h << 16);
    l = cvt_hi(x - hf);
}
// manual RNE split (prep kernels keep the verified path)
__device__ __forceinline__ void bf16split(float x, unsigned short& h, unsigned short& l) {
    unsigned u = __float_as_uint(x);
    unsigned hr = (u + 0x7FFFu + ((u >> 16) & 1u)) >> 16;
    float hf = __uint_as_float(hr << 16);
    float r = x - hf;
    unsigned v = __float_as_uint(r);
    unsigned lr = (v + 0x7FFFu + ((v >> 16) & 1u)) >> 16;
    h = (unsigned short)hr; l = (unsigned short)lr;
}

__global__ void pack_q(const float* __restrict__ Q,
                       unsigned short* __restrict__ qh, unsigned short* __restrict__ ql) {
    int g = blockIdx.x * blockDim.x + threadIdx.x;
    if (g >= Hh*19*10*64) return;
    int l = g & 63;
    int t = g >> 6;
    int ks = t % 10; t /= 10;
    int nt = t % 19; int h = t / 19;
    int e = 16*nt + (l & 15);
    int kbase = 32*ks + 8*(l >> 4);
    unsigned hp[4], lp[4];
    #pragma unroll
    for (int p = 0; p < 4; ++p) {
        int k0 = kbase + 2*p, k1 = k0 + 1;
        float x0 = (k0 < Dd && e < Dd) ? Q[h*Dd*Dd + k0*Dd + e] : 0.f;
        float x1 = (k1 < Dd && e < Dd) ? Q[h*Dd*Dd + k1*Dd + e] : 0.f;
        unsigned short h0,l0,h1,l1;
        bf16split(x0,h0,l0); bf16split(x1,h1,l1);
        hp[p] = (unsigned)h0 | ((unsigned)h1 << 16);
        lp[p] = (unsigned)l0 | ((unsigned)l1 << 16);
    }
    ((uint4*)qh)[g] = make_uint4(hp[0],hp[1],hp[2],hp[3]);
    ((uint4*)ql)[g] = make_uint4(lp[0],lp[1],lp[2],lp[3]);
}

__global__ void pack_v(const float* __restrict__ V,
                       unsigned short* __restrict__ vh, unsigned short* __restrict__ vl) {
    int g = blockIdx.x * blockDim.x + threadIdx.x;
    if (g >= Hh*2*10*64) return;
    int l = g & 63;
    int t = g >> 6;
    int ks = t % 10; t /= 10;
    int nt = t % 2; int h = t / 2;
    int f = 16*nt + (l & 15);
    int kbase = 32*ks + 8*(l >> 4);
    unsigned hp[4], lp[4];
    #pragma unroll
    for (int p = 0; p < 4; ++p) {
        int k0 = kbase + 2*p, k1 = k0 + 1;
        float x0 = (k0 < Dd && f < HDd) ? V[h*Dd*HDd + k0*HDd + f] : 0.f;
        float x1 = (k1 < Dd && f < HDd) ? V[h*Dd*HDd + k1*HDd + f] : 0.f;
        unsigned short h0,l0,h1,l1;
        bf16split(x0,h0,l0); bf16split(x1,h1,l1);
        hp[p] = (unsigned)h0 | ((unsigned)h1 << 16);
        lp[p] = (unsigned)l0 | ((unsigned)l1 << 16);
    }
    ((uint4*)vh)[g] = make_uint4(hp[0],hp[1],hp[2],hp[3]);
    ((uint4*)vl)[g] = make_uint4(lp[0],lp[1],lp[2],lp[3]);
}

// ---- main: one block per (b,h), 512 thr = 8 waves, LDS 81,920 B -> 2 blocks/CU ----
// Round-12 base (708us) + phase-3 rebalance: S split over waves 0-3 (one quadrant each,
// 30 MFMA), P on waves 4-7 (30 MFMA) -> phase-3 MFMA max halves, all waves busy.
// Raw S staged as bf16 hi/lo into DEAD chunks 8-15 of a1h/a1l (cols 64-127 post-swizzle,
// disjoint from alpha/P^T chunks 0-7), written only AFTER the phase-3 barrier (no race).
// VGPR must stay <= 64 (measured cliff at >64: occ 44% -> 24%).
__global__ __launch_bounds__(512, 2)
void mha_v10(const float* __restrict__ y, const int* __restrict__ seq,
             const unsigned short* __restrict__ qh, const unsigned short* __restrict__ ql,
             const unsigned short* __restrict__ vh, const unsigned short* __restrict__ vl,
             float* __restrict__ out)
{
    __shared__ __align__(16) unsigned short y_h[32*320], y_l[32*320];  // y bf16 hi/lo, swizzled
    __shared__ __align__(16) unsigned short a1h[32*320], a1l[32*320];  // a1; later alpha/P^T + S staging

    const int bid = blockIdx.x;
    const int h = bid >> 10, b = bid & 1023;   // b fastest -> consecutive blocks share Q[h] in L2
    const int tid = threadIdx.x;
    const int lane = tid & 63, wid = tid >> 6;
    const int lrow = lane & 15, lk = lane >> 4;
    const int l7 = lrow & 7;

    // ---- phase 1: y -> swizzled bf16 hi/lo LDS, float4-vectorized ----
    const float* yb = y + (size_t)b * (Ll * Dd);
    const float4 z4 = make_float4(0.f, 0.f, 0.f, 0.f);
    for (int idx4 = tid; idx4 < 32*80; idx4 += 512) {
        int row = idx4 / 80;
        int c4  = (idx4 - row*80) << 2;                 // chunks all-valid (<300) or all-pad
        float4 v = (row < Ll && c4 < Dd) ? *reinterpret_cast<const float4*>(yb + row*Dd + c4) : z4;
        unsigned short h0, l0, h1, l1, h2, l2, h3, l3;
        splitc(v.x, h0, l0);
        splitc(v.y, h1, l1);
        splitc(v.z, h2, l2);
        splitc(v.w, h3, l3);
        u16x4 hv, lv;
        hv[0] = h0; hv[1] = h1; hv[2] = h2; hv[3] = h3;
        lv[0] = l0; lv[1] = l1; lv[2] = l2; lv[3] = l3;
        int sidx = SW(row, c4);                         // 4 cols share one 8-chunk; 8B aligned
        *reinterpret_cast<u16x4*>(&y_h[sidx]) = hv;
        *reinterpret_cast<u16x4*>(&y_l[sidx]) = lv;
    }
    if (tid < 128) {   // zero a1 pad chunks 38,39 (cols 304..319) for phase-3 K-tail
        int r = tid & 31, c = 38 + ((tid >> 5) & 1);
        unsigned short* p = (tid >> 6) ? a1l : a1h;
        int sc = c ^ (r & 7);
        *((uint4*)&p[r*320 + sc*8]) = make_uint4(0,0,0,0);
    }
    __syncthreads();

    // ---- phase 2: a1 = y.Q (3-split MFMA); 38 half-tiles (nt, Mt), stride-8 over 8 waves ----
    for (int ht = wid; ht < 38; ht += 8) {
        const int nt = ht >> 1, Mt = ht & 1;
        f32x4 acc0 = (f32x4){0,0,0,0}, acc1 = (f32x4){0,0,0,0};
        const unsigned short* qhp = qh + (size_t)((h*19 + nt)*10)*512 + lane*8;
        const unsigned short* qlp = ql + (size_t)((h*19 + nt)*10)*512 + lane*8;
        const int arow = (16*Mt + lrow)*320;
        #pragma unroll
        for (int ks = 0; ks < 10; ++ks) {
            short8 bh = *(const short8*)(qhp + ks*512);
            short8 bl = *(const short8*)(qlp + ks*512);
            const int ia = arow + (((4*ks + lk) ^ l7) << 3);
            short8 ah = *(const short8*)&y_h[ia];
            short8 al = *(const short8*)&y_l[ia];
            if (ks & 1) {
                acc1 = __builtin_amdgcn_mfma_f32_16x16x32_bf16(ah, bh, acc1, 0,0,0);
                acc1 = __builtin_amdgcn_mfma_f32_16x16x32_bf16(al, bh, acc1, 0,0,0);
                acc1 = __builtin_amdgcn_mfma_f32_16x16x32_bf16(ah, bl, acc1, 0,0,0);
            } else {
                acc0 = __builtin_amdgcn_mfma_f32_16x16x32_bf16(ah, bh, acc0, 0,0,0);
                acc0 = __builtin_amdgcn_mfma_f32_16x16x32_bf16(al, bh, acc0, 0,0,0);
                acc0 = __builtin_amdgcn_mfma_f32_16x16x32_bf16(ah, bl, acc0, 0,0,0);
            }
        }
        f32x4 a = acc0 + acc1;
        const int col = 16*nt + lrow;                   // <= 303 always
        #pragma unroll
        for (int r = 0; r < 4; ++r) {
            int row = 16*Mt + 4*lk + r;
            unsigned short hv, lv; splitc(a[r], hv, lv);
            int sidx = SW(row, col);
            a1h[sidx] = hv;
            a1l[sidx] = lv;
        }
    }
    __syncthreads();

    // ---- phase 3: waves 0-3: one S quadrant each; waves 4-7: one P tile each (30 MFMA all) ----
    f32x4 Sq = (f32x4){0,0,0,0};   // S-wave quadrant result
    f32x4 Pacc = (f32x4){0,0,0,0}; // P-wave result

    if (wid < 4) {
        const int Mt = wid >> 1, Nt = wid & 1;
        f32x4 acc0 = (f32x4){0,0,0,0}, acc1 = (f32x4){0,0,0,0};
        const int arow = (16*Mt + lrow)*320;
        const int brow = (16*Nt + lrow)*320;
        #pragma unroll
        for (int ntp = 0; ntp < 10; ++ntp) {
            const int ch = ((4*ntp + lk) ^ l7) << 3;
            short8 ah = *(const short8*)&a1h[arow + ch];
            short8 al = *(const short8*)&a1l[arow + ch];
            short8 bh = *(const short8*)&y_h[brow + ch];
            short8 bl = *(const short8*)&y_l[brow + ch];
            if (ntp & 1) {
                acc1 = __builtin_amdgcn_mfma_f32_16x16x32_bf16(ah, bh, acc1, 0,0,0);
                acc1 = __builtin_amdgcn_mfma_f32_16x16x32_bf16(al, bh, acc1, 0,0,0);
                acc1 = __builtin_amdgcn_mfma_f32_16x16x32_bf16(ah, bl, acc1, 0,0,0);
            } else {
                acc0 = __builtin_amdgcn_mfma_f32_16x16x32_bf16(ah, bh, acc0, 0,0,0);
                acc0 = __builtin_amdgcn_mfma_f32_16x16x32_bf16(al, bh, acc0, 0,0,0);
                acc0 = __builtin_amdgcn_mfma_f32_16x16x32_bf16(ah, bl, acc0, 0,0,0);
            }
        }
        Sq = acc0 + acc1;
    } else {
        const int w = wid - 4, Mtp = w >> 1, Ntp = w & 1;
        f32x4 acc0 = (f32x4){0,0,0,0}, acc1 = (f32x4){0,0,0,0};
        const unsigned short* vhp = vh + (size_t)((h*2 + Ntp)*10)*512 + lane*8;
        const unsigned short* vlp = vl + (size_t)((h*2 + Ntp)*10)*512 + lane*8;
        const int arow = (16*Mtp + lrow)*320;
        #pragma unroll
        for (int ks = 0; ks < 10; ++ks) {
            short8 bh = *(const short8*)(vhp + ks*512);
            short8 bl = *(const short8*)(vlp + ks*512);
            int ia = arow + (((4*ks + lk) ^ l7) << 3);
            short8 ah = *(const short8*)&y_h[ia];
            short8 al = *(const short8*)&y_l[ia];
            if (ks & 1) {
                acc1 = __builtin_amdgcn_mfma_f32_16x16x32_bf16(ah, bh, acc1, 0,0,0);
                acc1 = __builtin_amdgcn_mfma_f32_16x16x32_bf16(al, bh, acc1, 0,0,0);
                acc1 = __builtin_amdgcn_mfma_f32_16x16x32_bf16(ah, bl, acc1, 0,0,0);
            } else {
                acc0 = __builtin_amdgcn_mfma_f32_16x16x32_bf16(ah, bh, acc0, 0,0,0);
                acc0 = __builtin_amdgcn_mfma_f32_16x16x32_bf16(al, bh, acc0, 0,0,0);
                acc0 = __builtin_amdgcn_mfma_f32_16x16x32_bf16(ah, bl, acc0, 0,0,0);
            }
        }
        Pacc = acc0 + acc1;
    }
    __syncthreads();   // a1 operand reads complete -> a1h/a1l writable

    // ---- phase 4a: S quadrants -> staging (chunks 8-15: col 64+); P^T -> a1h cols 0-31 ----
    if (wid < 4) {
        const int Mt = wid >> 1, Nt = wid & 1;
        #pragma unroll
        for (int r = 0; r < 4; ++r) {
            int row = 16*Mt + 4*lk + r;
            unsigned short hv, lv; splitc(Sq[r], hv, lv);
            int sidx = SW(row, 64 + 16*Nt + lrow);
            a1h[sidx] = hv;
            a1l[sidx] = lv;
        }
    } else {
        const int w = wid - 4, Mtp = w >> 1, Ntp = w & 1;
        #pragma unroll
        for (int r = 0; r < 4; ++r)
            a1h[SW(16*Ntp + lrow, 16*Mtp + 4*lk + r)] = cvt_hi(Pacc[r]);
    }
    __syncthreads();

    // ---- phase 4b: waves 0-1: softmax from staged S; alpha -> a1l cols 0-31 ----
    if (wid < 2) {
        const int Mt = wid;
        const float mk0 = (seq[b*Ll + lrow] > 0) ? 1.f : 0.f;
        const float mk1 = (lrow < 14) ? ((seq[b*Ll + 16 + lrow] > 0) ? 1.f : 0.f) : 0.f;
        float alf[2][4];
        #pragma unroll
        for (int r = 0; r < 4; ++r) {
            int row = 16*Mt + 4*lk + r;
            int i0 = SW(row, 64 + lrow);
            int i1 = SW(row, 80 + lrow);
            float s0 = __uint_as_float((unsigned)a1h[i0] << 16) + __uint_as_float((unsigned)a1l[i0] << 16);
            float s1 = __uint_as_float((unsigned)a1h[i1] << 16) + __uint_as_float((unsigned)a1l[i1] << 16);
            float v = fmaxf(s0, (lrow < 14) ? s1 : -3.4e38f);
            #pragma unroll
            for (int off = 8; off >= 1; off >>= 1)
                v = fmaxf(v, __shfl_xor(v, off, 64));
            float e0 = __expf(s0 - v);
            float e1 = __expf(s1 - v);
            float sum = e0 * mk0 + e1 * mk1;
            #pragma unroll
            for (int off = 8; off >= 1; off >>= 1)
                sum += __shfl_xor(sum, off, 64);
            float denom = sum + 1e-6f * __expf(-v);
            alf[0][r] = e0 / denom;
            alf[1][r] = (lrow < 14) ? e1 / denom : 0.f;   // zero artifact cols m=30,31
        }
        #pragma unroll
        for (int Nt = 0; Nt < 2; ++Nt)
            #pragma unroll
            for (int r = 0; r < 4; ++r)
                a1l[SW(16*Mt + 4*lk + r, 16*Nt + lrow)] = cvt_hi(alf[Nt][r]);
    }
    __syncthreads();

    // ---- phase 5: out = alpha . P ; waves 0-3 = quadrants ----
    if (wid < 4) {
        const int Mt = wid >> 1, Nt = wid & 1;
        short8 af = *(const short8*)&a1l[(16*Mt + lrow)*320 + ((lk ^ l7) << 3)];
        short8 pf = *(const short8*)&a1h[(16*Nt + lrow)*320 + ((lk ^ l7) << 3)];
        f32x4 O = __builtin_amdgcn_mfma_f32_16x16x32_bf16(af, pf, (f32x4){0,0,0,0}, 0,0,0);
        #pragma unroll
        for (int r = 0; r < 4; ++r) {
            int q = 16*Mt + 4*lk + r;
            int f = 16*Nt + lrow;
            if (q < Ll && f < HDd)
                out[(size_t)b*(Ll*Hh*HDd) + q*(Hh*HDd) + h*HDd + f] = O[r];
        }
    }
}

// ---- fallback (round-5 verified fp32 kernel), used if ws too small ----
__global__ __launch_bounds__(256, 3)
void mha_fused_fp32(const float* __restrict__ y,
                    const int* __restrict__ seq,
                    const float* __restrict__ Q,
                    const float* __restrict__ V,
                    float* __restrict__ out)
{
    __shared__ float ys[32][320];
    __shared__ float alphaS[32][33];
    __shared__ float Plds[32][20];
    __shared__ float maskSf[32];

    const int bid = blockIdx.x;
    const int h = bid >> 10;
    const int b = bid & 1023;
    const int tid = threadIdx.x;
    const int tj = tid & 31;
    const int ti = tid >> 5;
    const int r0 = ti * 4;

    const float* yb = y + b * (Ll * Dd);
    for (int i = tid; i < 32 * 320; i += 256) {
        int row = i / 320;
        int col = i - row * 320;
        float v = 0.f;
        if (row < Ll && col < Dd) v = yb[row * Dd + col];
        ys[row][col] = v;
    }
    if (tid < 32) {
        float m = 0.f;
        if (tid < Ll) m = (seq[b * Ll + tid] > 0) ? 1.f : 0.f;
        maskSf[tid] = m;
    }
    __syncthreads();

    float a1reg[4][10];
    #pragma unroll
    for (int r = 0; r < 4; ++r)
        #pragma unroll
        for (int k = 0; k < 10; ++k) a1reg[r][k] = 0.f;

    const float* Qh = Q + h * (Dd * Dd) + tj;
    for (int d0 = 0; d0 < Dd; d0 += 4) {
        float ysv[4][4];
        #pragma unroll
        for (int r = 0; r < 4; ++r) {
            float4 t = *reinterpret_cast<const float4*>(&ys[r0 + r][d0]);
            ysv[r][0] = t.x; ysv[r][1] = t.y; ysv[r][2] = t.z; ysv[r][3] = t.w;
        }
        #pragma unroll
        for (int dd = 0; dd < 4; ++dd) {
            const float* qp = Qh + (d0 + dd) * Dd;
            float qv[10];
            #pragma unroll
            for (int k = 0; k < 9; ++k) qv[k] = qp[32 * k];
            qv[9] = (tj < 12) ? qp[288] : 0.f;
            #pragma unroll
            for (int r = 0; r < 4; ++r) {
                float yd = ysv[r][dd];
                #pragma unroll
                for (int k = 0; k < 10; ++k)
                    a1reg[r][k] = fmaf(yd, qv[k], a1reg[r][k]);
            }
        }
    }

    float Sreg[4] = {0.f, 0.f, 0.f, 0.f};
    for (int m = 0; m < Ll; ++m) {
        float yv[10];
        #pragma unroll
        for (int k = 0; k < 10; ++k) yv[k] = ys[m][tj + 32 * k];
        float part[4];
        #pragma unroll
        for (int r = 0; r < 4; ++r) {
            float s = 0.f;
            #pragma unroll
            for (int k = 0; k < 10; ++k) s = fmaf(a1reg[r][k], yv[k], s);
            part[r] = s;
        }
        #pragma unroll
        for (int off = 16; off >= 1; off >>= 1)
            #pragma unroll
            for (int r = 0; r < 4; ++r)
                part[r] += __shfl_xor(part[r], off, 64);
        #pragma unroll
        for (int r = 0; r < 4; ++r)
            if (tj == m) Sreg[r] = part[r];
    }

    const float maskv = maskSf[tj];
    float Areg[4];
    #pragma unroll
    for (int r = 0; r < 4; ++r) {
        float v = (tj < Ll) ? Sreg[r] : -3.4e38f;
        #pragma unroll
        for (int off = 16; off >= 1; off >>= 1)
            v = fmaxf(v, __shfl_xor(v, off, 64));
        float e = __expf(Sreg[r] - v);
        float s = (tj < Ll) ? e * maskv : 0.f;
        #pragma unroll
        for (int off = 16; off >= 1; off >>= 1)
            s += __shfl_xor(s, off, 64);
        float denom = s + 1e-6f * __expf(-v);
        Areg[r] = e / denom;
    }
    #pragma unroll
    for (int r = 0; r < 4; ++r)
        if (r0 + r < Ll && tj < Ll) alphaS[r0 + r][tj] = Areg[r];

    float Pacc[4] = {0.f, 0.f, 0.f, 0.f};
    if (tj < HDd) {
        const float* Vh = V + h * (Dd * HDd) + tj;
        for (int d0 = 0; d0 < Dd; d0 += 4) {
            float ysv[4][4];
            #pragma unroll
            for (int r = 0; r < 4; ++r) {
                float4 t = *reinterpret_cast<const float4*>(&ys[r0 + r][d0]);
                ysv[r][0] = t.x; ysv[r][1] = t.y; ysv[r][2] = t.z; ysv[r][3] = t.w;
            }
            float vv[4];
            #pragma unroll
            for (int dd = 0; dd < 4; ++dd) vv[dd] = Vh[(d0 + dd) * HDd];
            #pragma unroll
            for (int r = 0; r < 4; ++r)
                #pragma unroll
                for (int dd = 0; dd < 4; ++dd)
                    Pacc[r] = fmaf(ysv[r][dd], vv[dd], Pacc[r]);
        }
    }
    #pragma unroll
    for (int r = 0; r < 4; ++r)
        if (tj < HDd && r0 + r < Ll) Plds[r0 + r][tj] = Pacc[r];
    __syncthreads();

    float* outb = out + b * (Ll * Hh * HDd) + h * HDd;
    for (int t = tid; t < Ll * HDd; t += 256) {
        int l = t / HDd;
        int f = t - l * HDd;
        float acc = 0.f;
        #pragma unroll
        for (int m = 0; m < Ll; ++m)
            acc = fmaf(alphaS[l][m], Plds[m][f], acc);
        outb[l * (Hh * HDd) + f] = acc;
    }
}

extern "C" void kernel_launch(void* const* d_in, const int* in_sizes, int n_in,
                              void* d_out, int out_size, void* d_ws, size_t ws_size,
                              hipStream_t stream) {
    (void)in_sizes; (void)n_in; (void)out_size;
    const float* y   = (const float*)d_in[0];
    const int*   seq = (const int*)d_in[1];
    const float* Q   = (const float*)d_in[2];
    const float* V   = (const float*)d_in[3];
    float* out = (float*)d_out;

    if (ws_size < WS_NEEDED) {
        hipLaunchKernelGGL(mha_fused_fp32, dim3(Bb * Hh), dim3(256), 0, stream, y, seq, Q, V, out);
        return;
    }

    unsigned short* qh = (unsigned short*)d_ws;
    unsigned short* ql = qh + QELEMS;
    unsigned short* vh = ql + QELEMS;
    unsigned short* vl = vh + VELEMS;

    pack_q<<<dim3((Hh*19*10*64 + 255)/256), dim3(256), 0, stream>>>(Q, qh, ql);
    pack_v<<<dim3((Hh*2*10*64 + 255)/256), dim3(256), 0, stream>>>(V, vh, vl);
    mha_v10<<<dim3(Bb * Hh), dim3(512), 0, stream>>>(y, seq, qh, ql, vh, vl, out);
}

// Round 22
// 704.161 us; speedup vs baseline: 1.0145x; 1.0035x over previous
//
#include <hip/hip_runtime.h>
#include <hip/hip_bf16.h>
#include <math.h>

#define Bb 1024
#define Ll 30
#define Dd 300
#define Hh 20
#define HDd 20

typedef __attribute__((ext_vector_type(8))) short short8;
typedef __attribute__((ext_vector_type(4))) float f32x4;
typedef __attribute__((ext_vector_type(4))) unsigned short u16x4;

// swizzled LDS index: [32 rows][320 u16], 8-u16 chunk XOR (verified: ~6.6e5 conflicts)
#define SW(row, col) ((row)*320 + ((((col) >> 3) ^ ((row) & 7)) << 3) + ((col) & 7))

// ws packing: Q frags [h][nt=19][ks=10][lane=64][8] hi,lo; V [h][nt=2][ks=10][64][8]
#define QELEMS (Hh*19*10*64*8)
#define VELEMS (Hh*2*10*64*8)
#define WS_NEEDED ((size_t)(2*QELEMS + 2*VELEMS) * 2)

__device__ __forceinline__ unsigned short cvt_hi(float x) {
    return __builtin_bit_cast(unsigned short, __float2bfloat16(x));
}
__device__ __forceinline__ void splitc(float x, unsigned short& h, unsigned short& l) {
    h = cvt_hi(x);
    float hf = __uint_as_float((unsigned)h << 16);
    l = cvt_hi(x - hf);
}
// manual RNE split (prep kernels keep the verified path)
__device__ __forceinline__ void bf16split(float x, unsigned short& h, unsigned short& l) {
    unsigned u = __float_as_uint(x);
    unsigned hr = (u + 0x7FFFu + ((u >> 16) & 1u)) >> 16;
    float hf = __uint_as_float(hr << 16);
    float r = x - hf;
    unsigned v = __float_as_uint(r);
    unsigned lr = (v + 0x7FFFu + ((v >> 16) & 1u)) >> 16;
    h = (unsigned short)hr; l = (unsigned short)lr;
}

__global__ void pack_q(const float* __restrict__ Q,
                       unsigned short* __restrict__ qh, unsigned short* __restrict__ ql) {
    int g = blockIdx.x * blockDim.x + threadIdx.x;
    if (g >= Hh*19*10*64) return;
    int l = g & 63;
    int t = g >> 6;
    int ks = t % 10; t /= 10;
    int nt = t % 19; int h = t / 19;
    int e = 16*nt + (l & 15);
    int kbase = 32*ks + 8*(l >> 4);
    unsigned hp[4], lp[4];
    #pragma unroll
    for (int p = 0; p < 4; ++p) {
        int k0 = kbase + 2*p, k1 = k0 + 1;
        float x0 = (k0 < Dd && e < Dd) ? Q[h*Dd*Dd + k0*Dd + e] : 0.f;
        float x1 = (k1 < Dd && e < Dd) ? Q[h*Dd*Dd + k1*Dd + e] : 0.f;
        unsigned short h0,l0,h1,l1;
        bf16split(x0,h0,l0); bf16split(x1,h1,l1);
        hp[p] = (unsigned)h0 | ((unsigned)h1 << 16);
        lp[p] = (unsigned)l0 | ((unsigned)l1 << 16);
    }
    ((uint4*)qh)[g] = make_uint4(hp[0],hp[1],hp[2],hp[3]);
    ((uint4*)ql)[g] = make_uint4(lp[0],lp[1],lp[2],lp[3]);
}

__global__ void pack_v(const float* __restrict__ V,
                       unsigned short* __restrict__ vh, unsigned short* __restrict__ vl) {
    int g = blockIdx.x * blockDim.x + threadIdx.x;
    if (g >= Hh*2*10*64) return;
    int l = g & 63;
    int t = g >> 6;
    int ks = t % 10; t /= 10;
    int nt = t % 2; int h = t / 2;
    int f = 16*nt + (l & 15);
    int kbase = 32*ks + 8*(l >> 4);
    unsigned hp[4], lp[4];
    #pragma unroll
    for (int p = 0; p < 4; ++p) {
        int k0 = kbase + 2*p, k1 = k0 + 1;
        float x0 = (k0 < Dd && f < HDd) ? V[h*Dd*HDd + k0*HDd + f] : 0.f;
        float x1 = (k1 < Dd && f < HDd) ? V[h*Dd*HDd + k1*HDd + f] : 0.f;
        unsigned short h0,l0,h1,l1;
        bf16split(x0,h0,l0); bf16split(x1,h1,l1);
        hp[p] = (unsigned)h0 | ((unsigned)h1 << 16);
        lp[p] = (unsigned)l0 | ((unsigned)l1 << 16);
    }
    ((uint4*)vh)[g] = make_uint4(hp[0],hp[1],hp[2],hp[3]);
    ((uint4*)vl)[g] = make_uint4(lp[0],lp[1],lp[2],lp[3]);
}

// ---- main: one block per (b,h), 512 thr = 8 waves, LDS 81,920 B -> 2 blocks/CU ----
// FINAL VERIFIED BEST (708.3/711.7/714.3 us across three runs; VGPR 56, occ 44%).
// Session-measured constraints:
//  - VGPR <= 64 required: occupancy cliff at >64 (44% -> 24%; rounds 13/17).
//  - Barrier phase-max arithmetic: per-phase MAXIMA add; cross-phase rebalance no-op (r16).
//  - Head-pairing / reg-prefetch push VGPR past the cliff (r13/r17).
//  - s_setprio null on barrier-locked waves (r19); S-quadrant split null (r21).
__global__ __launch_bounds__(512, 2)
void mha_v5(const float* __restrict__ y, const int* __restrict__ seq,
            const unsigned short* __restrict__ qh, const unsigned short* __restrict__ ql,
            const unsigned short* __restrict__ vh, const unsigned short* __restrict__ vl,
            float* __restrict__ out)
{
    __shared__ __align__(16) unsigned short y_h[32*320], y_l[32*320];  // y bf16 hi/lo, swizzled
    __shared__ __align__(16) unsigned short a1h[32*320], a1l[32*320];  // a1 hi/lo; later P^T / alpha

    const int bid = blockIdx.x;
    const int h = bid >> 10, b = bid & 1023;   // b fastest -> consecutive blocks share Q[h] in L2
    const int tid = threadIdx.x;
    const int lane = tid & 63, wid = tid >> 6;
    const int lrow = lane & 15, lk = lane >> 4;
    const int l7 = lrow & 7;

    // ---- phase 1: y -> swizzled bf16 hi/lo LDS, float4-vectorized ----
    const float* yb = y + (size_t)b * (Ll * Dd);
    const float4 z4 = make_float4(0.f, 0.f, 0.f, 0.f);
    for (int idx4 = tid; idx4 < 32*80; idx4 += 512) {
        int row = idx4 / 80;
        int c4  = (idx4 - row*80) << 2;                 // chunks all-valid (<300) or all-pad
        float4 v = (row < Ll && c4 < Dd) ? *reinterpret_cast<const float4*>(yb + row*Dd + c4) : z4;
        unsigned short h0, l0, h1, l1, h2, l2, h3, l3;
        splitc(v.x, h0, l0);
        splitc(v.y, h1, l1);
        splitc(v.z, h2, l2);
        splitc(v.w, h3, l3);
        u16x4 hv, lv;
        hv[0] = h0; hv[1] = h1; hv[2] = h2; hv[3] = h3;
        lv[0] = l0; lv[1] = l1; lv[2] = l2; lv[3] = l3;
        int sidx = SW(row, c4);                         // 4 cols share one 8-chunk; 8B aligned
        *reinterpret_cast<u16x4*>(&y_h[sidx]) = hv;
        *reinterpret_cast<u16x4*>(&y_l[sidx]) = lv;
    }
    if (tid < 128) {   // zero a1 pad chunks 38,39 (cols 304..319) for phase-3 K-tail
        int r = tid & 31, c = 38 + ((tid >> 5) & 1);
        unsigned short* p = (tid >> 6) ? a1l : a1h;
        int sc = c ^ (r & 7);
        *((uint4*)&p[r*320 + sc*8]) = make_uint4(0,0,0,0);
    }
    __syncthreads();

    // ---- phase 2: a1 = y.Q (3-split MFMA); 38 half-tiles (nt, Mt), stride-8 over 8 waves ----
    for (int ht = wid; ht < 38; ht += 8) {
        const int nt = ht >> 1, Mt = ht & 1;
        f32x4 acc0 = (f32x4){0,0,0,0}, acc1 = (f32x4){0,0,0,0};
        const unsigned short* qhp = qh + (size_t)((h*19 + nt)*10)*512 + lane*8;
        const unsigned short* qlp = ql + (size_t)((h*19 + nt)*10)*512 + lane*8;
        const int arow = (16*Mt + lrow)*320;
        #pragma unroll
        for (int ks = 0; ks < 10; ++ks) {
            short8 bh = *(const short8*)(qhp + ks*512);
            short8 bl = *(const short8*)(qlp + ks*512);
            const int ia = arow + (((4*ks + lk) ^ l7) << 3);
            short8 ah = *(const short8*)&y_h[ia];
            short8 al = *(const short8*)&y_l[ia];
            if (ks & 1) {
                acc1 = __builtin_amdgcn_mfma_f32_16x16x32_bf16(ah, bh, acc1, 0,0,0);
                acc1 = __builtin_amdgcn_mfma_f32_16x16x32_bf16(al, bh, acc1, 0,0,0);
                acc1 = __builtin_amdgcn_mfma_f32_16x16x32_bf16(ah, bl, acc1, 0,0,0);
            } else {
                acc0 = __builtin_amdgcn_mfma_f32_16x16x32_bf16(ah, bh, acc0, 0,0,0);
                acc0 = __builtin_amdgcn_mfma_f32_16x16x32_bf16(al, bh, acc0, 0,0,0);
                acc0 = __builtin_amdgcn_mfma_f32_16x16x32_bf16(ah, bl, acc0, 0,0,0);
            }
        }
        f32x4 a = acc0 + acc1;
        const int col = 16*nt + lrow;                   // <= 303 always
        #pragma unroll
        for (int r = 0; r < 4; ++r) {
            int row = 16*Mt + 4*lk + r;
            unsigned short hv, lv; splitc(a[r], hv, lv);
            int sidx = SW(row, col);
            a1h[sidx] = hv;
            a1l[sidx] = lv;
        }
    }
    __syncthreads();

    // ---- phase 3: waves 0-1: S = a1.y^T + in-register softmax; waves 2-5: P = y.V ----
    f32x4 Pacc = (f32x4){0,0,0,0};
    float alf[2][4];

    if (wid < 2) {
        const int Mt = wid;
        f32x4 acc[2][2];  // [Nt][parity]
        #pragma unroll
        for (int i = 0; i < 2; ++i) { acc[i][0] = (f32x4){0,0,0,0}; acc[i][1] = (f32x4){0,0,0,0}; }
        const int arow = (16*Mt + lrow)*320;
        #pragma unroll
        for (int ntp = 0; ntp < 10; ++ntp) {
            const int ch = ((4*ntp + lk) ^ l7) << 3;
            short8 ah = *(const short8*)&a1h[arow + ch];
            short8 al = *(const short8*)&a1l[arow + ch];
            #pragma unroll
            for (int Nt = 0; Nt < 2; ++Nt) {
                int ib = (16*Nt + lrow)*320 + ch;
                short8 bh = *(const short8*)&y_h[ib];
                short8 bl = *(const short8*)&y_l[ib];
                acc[Nt][ntp&1] = __builtin_amdgcn_mfma_f32_16x16x32_bf16(ah, bh, acc[Nt][ntp&1], 0,0,0);
                acc[Nt][ntp&1] = __builtin_amdgcn_mfma_f32_16x16x32_bf16(al, bh, acc[Nt][ntp&1], 0,0,0);
                acc[Nt][ntp&1] = __builtin_amdgcn_mfma_f32_16x16x32_bf16(ah, bl, acc[Nt][ntp&1], 0,0,0);
            }
        }
        f32x4 S0 = acc[0][0] + acc[0][1];
        f32x4 S1 = acc[1][0] + acc[1][1];
        // softmax-ratio (max-shifted; exact algebra vs reference). row q = 16Mt+4lk+r, col m = 16Nt+lrow.
        const float mk0 = (seq[b*Ll + lrow] > 0) ? 1.f : 0.f;
        const float mk1 = (lrow < 14) ? ((seq[b*Ll + 16 + lrow] > 0) ? 1.f : 0.f) : 0.f;
        #pragma unroll
        for (int r = 0; r < 4; ++r) {
            float s0 = S0[r], s1 = S1[r];
            float v = fmaxf(s0, (lrow < 14) ? s1 : -3.4e38f);
            #pragma unroll
            for (int off = 8; off >= 1; off >>= 1)
                v = fmaxf(v, __shfl_xor(v, off, 64));
            float e0 = __expf(s0 - v);
            float e1 = __expf(s1 - v);
            float sum = e0 * mk0 + e1 * mk1;
            #pragma unroll
            for (int off = 8; off >= 1; off >>= 1)
                sum += __shfl_xor(sum, off, 64);
            float denom = sum + 1e-6f * __expf(-v);
            alf[0][r] = e0 / denom;
            alf[1][r] = (lrow < 14) ? e1 / denom : 0.f;   // zero artifact cols m=30,31
        }
    } else if (wid < 6) {
        const int w = wid - 2, Mtp = w >> 1, Ntp = w & 1;
        f32x4 acc0 = (f32x4){0,0,0,0}, acc1 = (f32x4){0,0,0,0};
        const unsigned short* vhp = vh + (size_t)((h*2 + Ntp)*10)*512 + lane*8;
        const unsigned short* vlp = vl + (size_t)((h*2 + Ntp)*10)*512 + lane*8;
        const int arow = (16*Mtp + lrow)*320;
        #pragma unroll
        for (int ks = 0; ks < 10; ++ks) {
            short8 bh = *(const short8*)(vhp + ks*512);
            short8 bl = *(const short8*)(vlp + ks*512);
            int ia = arow + (((4*ks + lk) ^ l7) << 3);
            short8 ah = *(const short8*)&y_h[ia];
            short8 al = *(const short8*)&y_l[ia];
            if (ks & 1) {
                acc1 = __builtin_amdgcn_mfma_f32_16x16x32_bf16(ah, bh, acc1, 0,0,0);
                acc1 = __builtin_amdgcn_mfma_f32_16x16x32_bf16(al, bh, acc1, 0,0,0);
                acc1 = __builtin_amdgcn_mfma_f32_16x16x32_bf16(ah, bl, acc1, 0,0,0);
            } else {
                acc0 = __builtin_amdgcn_mfma_f32_16x16x32_bf16(ah, bh, acc0, 0,0,0);
                acc0 = __builtin_amdgcn_mfma_f32_16x16x32_bf16(al, bh, acc0, 0,0,0);
                acc0 = __builtin_amdgcn_mfma_f32_16x16x32_bf16(ah, bl, acc0, 0,0,0);
            }
        }
        Pacc = acc0 + acc1;
    }
    __syncthreads();   // S-waves done reading a1 -> a1h/a1l reusable

    // ---- phase 4: alpha -> a1l [q][m] bf16 (waves 0-1); P^T -> a1h [f][m] bf16 (waves 2-5) ----
    if (wid < 2) {
        const int Mt = wid;
        #pragma unroll
        for (int Nt = 0; Nt < 2; ++Nt)
            #pragma unroll
            for (int r = 0; r < 4; ++r)
                a1l[SW(16*Mt + 4*lk + r, 16*Nt + lrow)] = cvt_hi(alf[Nt][r]);
    } else if (wid < 6) {
        const int w = wid - 2, Mtp = w >> 1, Ntp = w & 1;
        #pragma unroll
        for (int r = 0; r < 4; ++r)
            a1h[SW(16*Ntp + lrow, 16*Mtp + 4*lk + r)] = cvt_hi(Pacc[r]);
        // P^T rows m=30,31 never written, but alpha cols 30,31 are zero -> unused
    }
    __syncthreads();

    // ---- phase 5: out = alpha . P ; waves 0-3 = quadrants ----
    if (wid < 4) {
        const int Mt = wid >> 1, Nt = wid & 1;
        short8 af = *(const short8*)&a1l[(16*Mt + lrow)*320 + ((lk ^ l7) << 3)];
        short8 pf = *(const short8*)&a1h[(16*Nt + lrow)*320 + ((lk ^ l7) << 3)];
        f32x4 O = __builtin_amdgcn_mfma_f32_16x16x32_bf16(af, pf, (f32x4){0,0,0,0}, 0,0,0);
        #pragma unroll
        for (int r = 0; r < 4; ++r) {
            int q = 16*Mt + 4*lk + r;
            int f = 16*Nt + lrow;
            if (q < Ll && f < HDd)
                out[(size_t)b*(Ll*Hh*HDd) + q*(Hh*HDd) + h*HDd + f] = O[r];
        }
    }
}

// ---- fallback (round-5 verified fp32 kernel), used if ws too small ----
__global__ __launch_bounds__(256, 3)
void mha_fused_fp32(const float* __restrict__ y,
                    const int* __restrict__ seq,
                    const float* __restrict__ Q,
                    const float* __restrict__ V,
                    float* __restrict__ out)
{
    __shared__ float ys[32][320];
    __shared__ float alphaS[32][33];
    __shared__ float Plds[32][20];
    __shared__ float maskSf[32];

    const int bid = blockIdx.x;
    const int h = bid >> 10;
    const int b = bid & 1023;
    const int tid = threadIdx.x;
    const int tj = tid & 31;
    const int ti = tid >> 5;
    const int r0 = ti * 4;

    const float* yb = y + b * (Ll * Dd);
    for (int i = tid; i < 32 * 320; i += 256) {
        int row = i / 320;
        int col = i - row * 320;
        float v = 0.f;
        if (row < Ll && col < Dd) v = yb[row * Dd + col];
        ys[row][col] = v;
    }
    if (tid < 32) {
        float m = 0.f;
        if (tid < Ll) m = (seq[b * Ll + tid] > 0) ? 1.f : 0.f;
        maskSf[tid] = m;
    }
    __syncthreads();

    float a1reg[4][10];
    #pragma unroll
    for (int r = 0; r < 4; ++r)
        #pragma unroll
        for (int k = 0; k < 10; ++k) a1reg[r][k] = 0.f;

    const float* Qh = Q + h * (Dd * Dd) + tj;
    for (int d0 = 0; d0 < Dd; d0 += 4) {
        float ysv[4][4];
        #pragma unroll
        for (int r = 0; r < 4; ++r) {
            float4 t = *reinterpret_cast<const float4*>(&ys[r0 + r][d0]);
            ysv[r][0] = t.x; ysv[r][1] = t.y; ysv[r][2] = t.z; ysv[r][3] = t.w;
        }
        #pragma unroll
        for (int dd = 0; dd < 4; ++dd) {
            const float* qp = Qh + (d0 + dd) * Dd;
            float qv[10];
            #pragma unroll
            for (int k = 0; k < 9; ++k) qv[k] = qp[32 * k];
            qv[9] = (tj < 12) ? qp[288] : 0.f;
            #pragma unroll
            for (int r = 0; r < 4; ++r) {
                float yd = ysv[r][dd];
                #pragma unroll
                for (int k = 0; k < 10; ++k)
                    a1reg[r][k] = fmaf(yd, qv[k], a1reg[r][k]);
            }
        }
    }

    float Sreg[4] = {0.f, 0.f, 0.f, 0.f};
    for (int m = 0; m < Ll; ++m) {
        float yv[10];
        #pragma unroll
        for (int k = 0; k < 10; ++k) yv[k] = ys[m][tj + 32 * k];
        float part[4];
        #pragma unroll
        for (int r = 0; r < 4; ++r) {
            float s = 0.f;
            #pragma unroll
            for (int k = 0; k < 10; ++k) s = fmaf(a1reg[r][k], yv[k], s);
            part[r] = s;
        }
        #pragma unroll
        for (int off = 16; off >= 1; off >>= 1)
            #pragma unroll
            for (int r = 0; r < 4; ++r)
                part[r] += __shfl_xor(part[r], off, 64);
        #pragma unroll
        for (int r = 0; r < 4; ++r)
            if (tj == m) Sreg[r] = part[r];
    }

    const float maskv = maskSf[tj];
    float Areg[4];
    #pragma unroll
    for (int r = 0; r < 4; ++r) {
        float v = (tj < Ll) ? Sreg[r] : -3.4e38f;
        #pragma unroll
        for (int off = 16; off >= 1; off >>= 1)
            v = fmaxf(v, __shfl_xor(v, off, 64));
        float e = __expf(Sreg[r] - v);
        float s = (tj < Ll) ? e * maskv : 0.f;
        #pragma unroll
        for (int off = 16; off >= 1; off >>= 1)
            s += __shfl_xor(s, off, 64);
        float denom = s + 1e-6f * __expf(-v);
        Areg[r] = e / denom;
    }
    #pragma unroll
    for (int r = 0; r < 4; ++r)
        if (r0 + r < Ll && tj < Ll) alphaS[r0 + r][tj] = Areg[r];

    float Pacc[4] = {0.f, 0.f, 0.f, 0.f};
    if (tj < HDd) {
        const float* Vh = V + h * (Dd * HDd) + tj;
        for (int d0 = 0; d0 < Dd; d0 += 4) {
            float ysv[4][4];
            #pragma unroll
            for (int r = 0; r < 4; ++r) {
                float4 t = *reinterpret_cast<const float4*>(&ys[r0 + r][d0]);
                ysv[r][0] = t.x; ysv[r][1] = t.y; ysv[r][2] = t.z; ysv[r][3] = t.w;
            }
            float vv[4];
            #pragma unroll
            for (int dd = 0; dd < 4; ++dd) vv[dd] = Vh[(d0 + dd) * HDd];
            #pragma unroll
            for (int r = 0; r < 4; ++r)
                #pragma unroll
                for (int dd = 0; dd < 4; ++dd)
                    Pacc[r] = fmaf(ysv[r][dd], vv[dd], Pacc[r]);
        }
    }
    #pragma unroll
    for (int r = 0; r < 4; ++r)
        if (tj < HDd && r0 + r < Ll) Plds[r0 + r][tj] = Pacc[r];
    __syncthreads();

    float* outb = out + b * (Ll * Hh * HDd) + h * HDd;
    for (int t = tid; t < Ll * HDd; t += 256) {
        int l = t / HDd;
        int f = t - l * HDd;
        float acc = 0.f;
        #pragma unroll
        for (int m = 0; m < Ll; ++m)
            acc = fmaf(alphaS[l][m], Plds[m][f], acc);
        outb[l * (Hh * HDd) + f] = acc;
    }
}

extern "C" void kernel_launch(void* const* d_in, const int* in_sizes, int n_in,
                              void* d_out, int out_size, void* d_ws, size_t ws_size,
                              hipStream_t stream) {
    (void)in_sizes; (void)n_in; (void)out_size;
    const float* y   = (const float*)d_in[0];
    const int*   seq = (const int*)d_in[1];
    const float* Q   = (const float*)d_in[2];
    const float* V   = (const float*)d_in[3];
    float* out = (float*)d_out;

    if (ws_size < WS_NEEDED) {
        hipLaunchKernelGGL(mha_fused_fp32, dim3(Bb * Hh), dim3(256), 0, stream, y, seq, Q, V, out);
        return;
    }

    unsigned short* qh = (unsigned short*)d_ws;
    unsigned short* ql = qh + QELEMS;
    unsigned short* vh = ql + QELEMS;
    unsigned short* vl = vh + VELEMS;

    pack_q<<<dim3((Hh*19*10*64 + 255)/256), dim3(256), 0, stream>>>(Q, qh, ql);
    pack_v<<<dim3((Hh*2*10*64 + 255)/256), dim3(256), 0, stream>>>(V, vh, vl);
    mha_v5<<<dim3(Bb * Hh), dim3(512), 0, stream>>>(y, seq, qh, ql, vh, vl, out);
}